// Round 7
// baseline (103.255 us; speedup 1.0000x reference)
//
#include <hip/hip_runtime.h>

#define N 8192
#define Dk 128
#define EPSC 1e-6f
#define MARGIN 0.2f
#define NCLS 1000

typedef __attribute__((ext_vector_type(8))) short bf16x8;
typedef __attribute__((ext_vector_type(4))) float f32x4;

__device__ __forceinline__ unsigned short f2bf(float f) {
    unsigned u = __float_as_uint(f);
    u = (u + 0x7FFFu + ((u >> 16) & 1u)) >> 16;  // RNE fp32->bf16
    return (unsigned short)u;
}
// monotone float->uint encoding so atomicMax/Min on unsigned orders like float
__device__ __forceinline__ unsigned enc(float f) {
    unsigned u = __float_as_uint(f);
    return (u & 0x80000000u) ? ~u : (u | 0x80000000u);
}
__device__ __forceinline__ float dec(unsigned u) {
    return __uint_as_float((u & 0x80000000u) ? (u & 0x7FFFFFFFu) : ~u);
}

__device__ __forceinline__ void gl_lds16(const void* src, void* lds_dst) {
    __builtin_amdgcn_global_load_lds(
        (const __attribute__((address_space(1))) unsigned*)src,
        (__attribute__((address_space(3))) unsigned*)lds_dst, 16, 0, 0);
}

// S0: class histogram (cnt zeroed by hipMemsetAsync before this)
__global__ void hist_kernel(const int* __restrict__ tgt, int* __restrict__ cnt) {
    int i = blockIdx.x * 1024 + threadIdx.x;
    if (i < N) atomicAdd(&cnt[tgt[i]], 1);
}

// S1: exclusive prefix sum over 1000 class counts -> cursor (scatter base) and
// SEclass[c] = start | (end<<16) (start,end <= 8192 fit 14 bits)
__global__ void scan_kernel(const int* __restrict__ cnt, int* __restrict__ cursor,
                            int* __restrict__ SEclass) {
    __shared__ int sbuf[1024];
    int t = threadIdx.x;
    int v = (t < NCLS) ? cnt[t] : 0;
    sbuf[t] = v;
    __syncthreads();
#pragma unroll
    for (int off = 1; off < 1024; off <<= 1) {
        int add = (t >= off) ? sbuf[t - off] : 0;
        __syncthreads();
        sbuf[t] += add;
        __syncthreads();
    }
    if (t < NCLS) {
        int base = sbuf[t] - v;  // exclusive
        cursor[t] = base;
        SEclass[t] = base | ((base + v) << 16);
    }
}

// Kernel A: CLASS-SORTED, SWIZZLED bf16 copy of x. Row r scatters to dest =
// cursor[class]++ so same-class rows are contiguous; per-dest P, Qf (-Q/2),
// SE (class range), stat init. One wave per original row.
__global__ void prep_kernel(const float* __restrict__ x, const int* __restrict__ tgt,
                            int* __restrict__ cursor, const int* __restrict__ SEclass,
                            unsigned short* __restrict__ Xb, float* __restrict__ Qf,
                            float* __restrict__ P, int* __restrict__ SE,
                            unsigned* __restrict__ wsHp, unsigned* __restrict__ wsMn) {
    int row = blockIdx.x * 4 + (threadIdx.x >> 6);
    int l = threadIdx.x & 63;
    const float2 v = *reinterpret_cast<const float2*>(&x[row * Dk + l * 2]);
    float sq = fmaf(v.x, v.x, v.y * v.y);
    float s = v.x + v.y;
    ushort2 a;
    a.x = f2bf(v.x);
    a.y = f2bf(v.y);
    int dest = 0, se = 0;
    if (l == 0) {
        int c = tgt[row];
        dest = atomicAdd(&cursor[c], 1);  // any within-class order is valid
        se = SEclass[c];
    }
    dest = __shfl(dest, 0);
    se = __shfl(se, 0);
    int c_phys = (l >> 2) ^ (dest & 7);  // swizzle keyed on DEST row (main reads by dest)
    *reinterpret_cast<ushort2*>(&Xb[dest * Dk + c_phys * 8 + 2 * (l & 3)]) = a;
#pragma unroll
    for (int m = 32; m >= 1; m >>= 1) {
        sq += __shfl_xor(sq, m);
        s += __shfl_xor(s, m);
    }
    if (l == 0) {
        P[dest] = sq - 2.0f * EPSC * s;
        float Qj = sq + 2.0f * EPSC * s + (float)Dk * EPSC * EPSC;
        Qf[dest] = -0.5f * Qj;
        SE[dest] = se;
        wsHp[dest] = 0xFF800000u;  // enc(+inf): identity for MIN (hardest_pos = min acc)
        wsMn[dest] = 0x007FFFFFu;  // enc(-inf): identity for MAX (hardest_neg = max acc)
    }
}

// Kernel B: round-6 structure (ti=2, 4 waves/SIMD, T4 counted-vmcnt barrier, T5
// setprio) with the CLASS-SORTED THIN EPILOGUE. Rows are class-sorted, so row
// dest's same-class cols are exactly [start,end) (SE[dest]); a wave's 32
// consecutive rows have nondecreasing start/end -> wave band = [SE[rbase].s,
// SE[rbase+31].e). Per step ONE wave-uniform scalar test: if [jb,jb+64) misses
// the band (~98% of steps), epilogue = 32 pure fmax (no v_cmp/ballot/branch,
// no class vectors). In-band steps do exact per-element range tests.
// hp = min acc over in-band (incl diagonal, = round-6 semantics); mn = max acc
// over out-of-band. Mean over rows is permutation-invariant: no unsort needed.
__global__ __launch_bounds__(256, 4) void main_kernel(
        const unsigned short* __restrict__ Xb, const float* __restrict__ Qf,
        const int* __restrict__ SE,
        unsigned* __restrict__ wsHp, unsigned* __restrict__ wsMn) {
    __shared__ unsigned short Bs[2][64 * Dk];  // 2 x 16 KB
    __shared__ float Qs[2][256];               // 2 x 1 KB (upper 192 = staging slack)

    const int tid = threadIdx.x;
    const int w = tid >> 6;
    const int lane = tid & 63;
    const int n = lane & 15;
    const int q = lane >> 4;
    const int sw = n & 7;  // swizzle key: (global row)&7 == n&7 for rows this lane reads

    const int ig = (int)blockIdx.x >> 4;   // 0..63: row group of 128
    const int js = (int)blockIdx.x & 15;   // 0..15: col slice of 512
    const int rbase = ig * 128 + 32 * w;   // this wave's 32 anchor rows

    const bf16x8* Xv = reinterpret_cast<const bf16x8*>(Xb);

    // Persistent A fragments: 32 rows x K=128 (32 VGPRs)
    bf16x8 Af[2][4];
#pragma unroll
    for (int ti = 0; ti < 2; ++ti)
#pragma unroll
        for (int kk = 0; kk < 4; ++kk)
            Af[ti][kk] = Xv[(rbase + 16 * ti + n) * 16 + ((q + 4 * kk) ^ sw)];

    // class ranges for this lane's 8 row-slots (packed start|end<<16)
    unsigned sePack[8];
#pragma unroll
    for (int ti = 0; ti < 2; ++ti) {
        int4 s4 = *reinterpret_cast<const int4*>(&SE[rbase + 16 * ti + 4 * q]);
        sePack[4 * ti + 0] = (unsigned)s4.x;
        sePack[4 * ti + 1] = (unsigned)s4.y;
        sePack[4 * ti + 2] = (unsigned)s4.z;
        sePack[4 * ti + 3] = (unsigned)s4.w;
    }
    // wave-uniform band: start nondecreasing, end nondecreasing in sorted order
    const int uS = SE[rbase] & 0xffff;
    const int uE = ((unsigned)SE[rbase + 31]) >> 16;

    float hp[8], mn[8];
#pragma unroll
    for (int s = 0; s < 8; ++s) {
        hp[s] = INFINITY;
        mn[s] = -INFINITY;
    }

    // async stage of step's B tile (16 KB) + Qf (256 B used) into buffer step&1
    auto stage = [&](int step) {
        const int jb = js * 512 + step * 64;
        const int buf = step & 1;
#pragma unroll
        for (int t = 0; t < 4; ++t)  // wave w stages rows 16w+4t .. 16w+4t+3
            gl_lds16(&Xb[(jb + 16 * w + 4 * t) * Dk] + lane * 8,
                     &Bs[buf][(16 * w + 4 * t) * Dk]);
        if (w == 0)  // 1 KB instr covers Qf[jb..jb+255]; upper 3/4 = staging slack
            gl_lds16(reinterpret_cast<const char*>(&Qf[jb]) + lane * 16,
                     &Qs[buf][0]);
    };

    stage(0);

    for (int step = 0; step < 8; ++step) {
        const int buf = step & 1;
        const int jb = js * 512 + step * 64;
        if (step < 7) {
            stage(step + 1);  // issue next-step prefetch BEFORE the wait
            // wait for stage(step) only; stage(step+1)'s L loads stay in flight
            if (w == 0)
                asm volatile("s_waitcnt vmcnt(5)" ::: "memory");
            else
                asm volatile("s_waitcnt vmcnt(4)" ::: "memory");
        } else {
            asm volatile("s_waitcnt vmcnt(0)" ::: "memory");
        }
        __builtin_amdgcn_sched_barrier(0);
        __builtin_amdgcn_s_barrier();
        __builtin_amdgcn_sched_barrier(0);

        float Qv[4];
#pragma unroll
        for (int tj = 0; tj < 4; ++tj) Qv[tj] = Qs[buf][16 * tj + n];  // = -Q_j/2

        f32x4 acc[2][4];
#pragma unroll
        for (int ti = 0; ti < 2; ++ti)
#pragma unroll
            for (int tj = 0; tj < 4; ++tj) acc[ti][tj] = Qv[tj];

#pragma unroll
        for (int kk = 0; kk < 4; ++kk) {
            bf16x8 Bf[4];
#pragma unroll
            for (int tj = 0; tj < 4; ++tj)
                Bf[tj] = *reinterpret_cast<const bf16x8*>(
                    &Bs[buf][(16 * tj + n) * Dk + (((q + 4 * kk) ^ sw) << 3)]);
            __builtin_amdgcn_s_setprio(1);
#pragma unroll
            for (int ti = 0; ti < 2; ++ti)
#pragma unroll
                for (int tj = 0; tj < 4; ++tj)
                    acc[ti][tj] = __builtin_amdgcn_mfma_f32_16x16x32_bf16(Af[ti][kk], Bf[tj],
                                                                          acc[ti][tj], 0, 0, 0);
            __builtin_amdgcn_s_setprio(0);
        }

        // THIN epilogue: acc elem r is (row rbase+16ti+4q+r, col jb+16tj+n)
        if ((jb < uE) && (uS < jb + 64)) {
            // in-band step (~2%): exact per-element class-range test
#pragma unroll
            for (int tj = 0; tj < 4; ++tj) {
                int j = jb + 16 * tj + n;
#pragma unroll
                for (int ti = 0; ti < 2; ++ti) {
                    f32x4 v = acc[ti][tj];
#pragma unroll
                    for (int r = 0; r < 4; ++r) {
                        unsigned se = sePack[4 * ti + r];
                        int inb = (j >= (int)(se & 0xffffu)) && (j < (int)(se >> 16));
                        hp[4 * ti + r] = fminf(hp[4 * ti + r], inb ? v[r] : INFINITY);
                        mn[4 * ti + r] = fmaxf(mn[4 * ti + r], inb ? -INFINITY : v[r]);
                    }
                }
            }
        } else {
            // fast path (~98%): all cols out-of-band -> pure fmax, no compares
#pragma unroll
            for (int tj = 0; tj < 4; ++tj)
#pragma unroll
                for (int ti = 0; ti < 2; ++ti) {
                    f32x4 v = acc[ti][tj];
                    mn[4 * ti + 0] = fmaxf(mn[4 * ti + 0], v[0]);
                    mn[4 * ti + 1] = fmaxf(mn[4 * ti + 1], v[1]);
                    mn[4 * ti + 2] = fmaxf(mn[4 * ti + 2], v[2]);
                    mn[4 * ti + 3] = fmaxf(mn[4 * ti + 3], v[3]);
                }
        }
    }

    // reduce across the 16 col-lanes; lane n==0 of each quad commits rows 4q+r
#pragma unroll
    for (int m = 1; m <= 8; m <<= 1) {
#pragma unroll
        for (int s = 0; s < 8; ++s) {
            hp[s] = fminf(hp[s], __shfl_xor(hp[s], m));
            mn[s] = fmaxf(mn[s], __shfl_xor(mn[s], m));
        }
    }
    if (n == 0) {
#pragma unroll
        for (int ti = 0; ti < 2; ++ti) {
#pragma unroll
            for (int r = 0; r < 4; ++r) {
                int i = rbase + 16 * ti + 4 * q + r;
                atomicMin(&wsHp[i], enc(hp[4 * ti + r]));
                atomicMax(&wsMn[i], enc(mn[4 * ti + r]));
            }
        }
    }
}

// Kernel C: single block, vectorized loads, writes out directly (sorted order;
// the mean is permutation-invariant)
__global__ void finish_kernel(const float* __restrict__ P,
                              const unsigned* __restrict__ wsHp,
                              const unsigned* __restrict__ wsMn,
                              float* __restrict__ out) {
    int t = threadIdx.x;  // 1024 threads, thread t handles i in [8t, 8t+8)
    float sum = 0.0f;
#pragma unroll
    for (int h = 0; h < 2; ++h) {
        int base = 8 * t + 4 * h;
        float4 Pv = *reinterpret_cast<const float4*>(&P[base]);
        uint4 Hv = *reinterpret_cast<const uint4*>(&wsHp[base]);
        uint4 Mv = *reinterpret_cast<const uint4*>(&wsMn[base]);
        const float* Pf = &Pv.x;
        const unsigned* Hu = &Hv.x;
        const unsigned* Mu = &Mv.x;
#pragma unroll
        for (int k = 0; k < 4; ++k) {
            float hp = sqrtf(fmaxf(fmaf(-2.0f, dec(Hu[k]), Pf[k]), 0.0f));
            float hn = sqrtf(fmaxf(fmaf(-2.0f, dec(Mu[k]), Pf[k]), 0.0f));
            sum += fmaxf(hp - hn + MARGIN, 0.0f);
        }
    }
#pragma unroll
    for (int m = 32; m >= 1; m >>= 1) sum += __shfl_xor(sum, m);
    __shared__ float ws[16];
    if ((t & 63) == 0) ws[t >> 6] = sum;
    __syncthreads();
    if (t == 0) {
        float tot = 0.0f;
#pragma unroll
        for (int i = 0; i < 16; ++i) tot += ws[i];
        out[0] = tot * (1.0f / (float)N);
    }
}

extern "C" void kernel_launch(void* const* d_in, const int* in_sizes, int n_in,
                              void* d_out, int out_size, void* d_ws, size_t ws_size,
                              hipStream_t stream) {
    const float* x = (const float*)d_in[0];
    const int* tgt = (const int*)d_in[1];
    float* out = (float*)d_out;

    char* ws = (char*)d_ws;
    const size_t xb = (size_t)N * Dk * 2;  // 2 MB class-sorted swizzled bf16 copy
    unsigned short* Xb = (unsigned short*)ws;
    float* Qf = (float*)(ws + xb);
    float* P = (float*)(ws + xb + (size_t)N * 4);
    unsigned* wsHp = (unsigned*)(ws + xb + (size_t)N * 8);
    unsigned* wsMn = (unsigned*)(ws + xb + (size_t)N * 12);
    int* SE = (int*)(ws + xb + (size_t)N * 16);
    int* cursor = (int*)(ws + xb + (size_t)N * 20);
    int* SEclass = (int*)(ws + xb + (size_t)N * 20 + 4096);
    int* cnt = (int*)(ws + xb + (size_t)N * 20 + 8192);

    hipMemsetAsync(cnt, 0, 4096, stream);
    hist_kernel<<<N / 1024, 1024, 0, stream>>>(tgt, cnt);
    scan_kernel<<<1, 1024, 0, stream>>>(cnt, cursor, SEclass);
    prep_kernel<<<N / 4, 256, 0, stream>>>(x, tgt, cursor, SEclass, Xb, Qf, P, SE,
                                           wsHp, wsMn);
    main_kernel<<<1024, 256, 0, stream>>>(Xb, Qf, SE, wsHp, wsMn);
    finish_kernel<<<1, 1024, 0, stream>>>(P, wsHp, wsMn, out);
}